// Round 1
// baseline (4094.843 us; speedup 1.0000x reference)
//
#include <hip/hip_runtime.h>
#include <cstdint>
#include <cstddef>

typedef _Float16 half2_t __attribute__((ext_vector_type(2)));
typedef _Float16 half4_t __attribute__((ext_vector_type(4)));
typedef _Float16 half8_t __attribute__((ext_vector_type(8)));
typedef float    float4_t __attribute__((ext_vector_type(4)));

#define NB 32
#define NR 196
#define DE 512
#define DD 512
#define NV 32000
#define NT 64
#define NG 2048
#define CAPLEN 65

#if defined(__has_builtin)
#if __has_builtin(__builtin_amdgcn_fdot2)
#define HAS_FDOT2 1
#endif
#endif

__device__ __forceinline__ float fdot2f(half2_t a, half2_t b, float c) {
#ifdef HAS_FDOT2
  return __builtin_amdgcn_fdot2(a, b, c, false);
#else
  return c + (float)a[0]*(float)b[0] + (float)a[1]*(float)b[1];
#endif
}

__device__ __forceinline__ float fast_tanh(float x) {
  float e = __expf(2.f*x);
  return 1.f - 2.f/(e + 1.f);
}
__device__ __forceinline__ float fast_sig(float x) {
  return 1.f/(1.f + __expf(-x));
}

// ---------- fp32 -> fp16 convert (n % 4 == 0) ----------
__global__ void cvt_k(const float* __restrict__ s, _Float16* __restrict__ d, int n) {
  int i = (blockIdx.x*blockDim.x + threadIdx.x)*4;
  if (i < n) {
    float4 v = *(const float4*)(s + i);
    half4_t h;
    h[0] = (_Float16)v.x; h[1] = (_Float16)v.y; h[2] = (_Float16)v.z; h[3] = (_Float16)v.w;
    *(half4_t*)(d + i) = h;
  }
}

__global__ void bias_sum_k(const float* __restrict__ a, const float* __restrict__ b,
                           float* __restrict__ o) {
  int i = blockIdx.x*blockDim.x + threadIdx.x;
  if (i < NG) o[i] = a[i] + b[i];
}

// gather embeddings for all (t,b): row r = t*NB + b, token = captions[b][t]
__global__ void gather_emb_k(const float* __restrict__ emb, const int* __restrict__ cap,
                             _Float16* __restrict__ X) {
  int r = blockIdx.x;
  int t = r >> 5, b = r & 31;
  int tok = cap[b*CAPLEN + t];
  const float* s = emb + (size_t)tok*DE;
  _Float16* d = X + (size_t)r*DE;
  for (int k = threadIdx.x; k < DE; k += blockDim.x) d[k] = (_Float16)s[k];
}

// feat_mean -> h0, c0 (fp32 exact; one wg per batch element)
__global__ void init_state_k(const float* __restrict__ imgf,
                             const float* __restrict__ Wh0, const float* __restrict__ bh0,
                             const float* __restrict__ Wc0, const float* __restrict__ bc0,
                             float* __restrict__ c_state, _Float16* __restrict__ h0h) {
  __shared__ float fm[DE];
  int b = blockIdx.x, tid = threadIdx.x;
  for (int dI = tid; dI < DE; dI += blockDim.x) {
    float s = 0.f;
    const float* p = imgf + ((size_t)b*NR)*DE + dI;
    for (int n = 0; n < NR; n++) s += p[(size_t)n*DE];
    fm[dI] = s * (1.f/196.f);
  }
  __syncthreads();
  for (int dI = tid; dI < DD; dI += blockDim.x) {
    const float* wh = Wh0 + (size_t)dI*DE;
    const float* wc = Wc0 + (size_t)dI*DE;
    float h = bh0[dI], c = bc0[dI];
    for (int k = 0; k < DE; k++) { h += fm[k]*wh[k]; c += fm[k]*wc[k]; }
    h0h[b*DD + dI] = (_Float16)h;
    c_state[b*DD + dI] = c;
  }
}

// Per-step attention: one wg per b. hW -> e (tanh) -> softmax -> ctx, writes alpha to out.
__global__ void __launch_bounds__(512) att_k(const _Float16* __restrict__ h_in,
    const _Float16* __restrict__ Wdec_h, const _Float16* __restrict__ fproj_h,
    const _Float16* __restrict__ imgf_h, const float* __restrict__ v_att,
    _Float16* __restrict__ ctx_h, float* __restrict__ out_alpha, int t) {
  __shared__ _Float16 hl[DD];
  __shared__ float vl[DD];
  __shared__ float hw[DD];
  __shared__ float epart[392];
  __shared__ float red[256];
  __shared__ float ea[256];
  int b = blockIdx.x, tid = threadIdx.x;
  hl[tid] = h_in[b*DD + tid];
  vl[tid] = v_att[tid];
  __syncthreads();
  // hW[d] = h . Wdec[d,:]
  {
    const half8_t* wr = (const half8_t*)(Wdec_h + (size_t)tid*DD);
    const half2_t* h2 = (const half2_t*)hl;
    float acc = 0.f;
    for (int k8 = 0; k8 < DD/8; k8++) {
      half8_t w8 = wr[k8];
      const half2_t* wp = (const half2_t*)&w8;
      int kb = k8*4;
      acc = fdot2f(wp[0], h2[kb+0], acc);
      acc = fdot2f(wp[1], h2[kb+1], acc);
      acc = fdot2f(wp[2], h2[kb+2], acc);
      acc = fdot2f(wp[3], h2[kb+3], acc);
    }
    hw[tid] = acc;
  }
  __syncthreads();
  // e[n] partials: thread = (n, half-of-d)
  if (tid < 392) {
    int n = tid >> 1, dh = (tid & 1) << 8;
    const half8_t* fp8 = (const half8_t*)(fproj_h + ((size_t)b*NR + n)*DD + dh);
    float ep = 0.f;
    for (int k8 = 0; k8 < 32; k8++) {
      half8_t f8 = fp8[k8];
      #pragma unroll
      for (int j = 0; j < 8; j++) {
        int dI = dh + k8*8 + j;
        ep += vl[dI] * fast_tanh((float)f8[j] + hw[dI]);
      }
    }
    epart[tid] = ep;
  }
  __syncthreads();
  if (tid < 256) {
    float e = (tid < NR) ? (epart[2*tid] + epart[2*tid+1]) : -1e30f;
    red[tid] = e;
    ea[tid] = e;
  }
  __syncthreads();
  for (int s = 128; s > 0; s >>= 1) {
    if (tid < s) red[tid] = fmaxf(red[tid], red[tid+s]);
    __syncthreads();
  }
  float mx = red[0];
  __syncthreads();
  if (tid < 256) {
    float ex = (tid < NR) ? __expf(ea[tid] - mx) : 0.f;
    ea[tid] = ex;
    red[tid] = ex;
  }
  __syncthreads();
  for (int s = 128; s > 0; s >>= 1) {
    if (tid < s) red[tid] += red[tid+s];
    __syncthreads();
  }
  float inv = 1.f / red[0];
  if (tid < NR) {
    float a = ea[tid] * inv;
    ea[tid] = a;
    out_alpha[((size_t)b*NT + t)*NR + tid] = a;
  }
  __syncthreads();
  // ctx[d] = sum_n alpha[n] * image_features[b,n,d]
  {
    const _Float16* ip = imgf_h + ((size_t)b*NR)*DE + tid;
    float acc = 0.f;
    for (int n = 0; n < NR; n++) acc += ea[n] * (float)ip[(size_t)n*DE];
    ctx_h[b*DE + tid] = (_Float16)acc;
  }
}

// Per-step gates + LSTM pointwise. One wg per 2 hidden dims (256 wgs).
// thread tid = b*8 + rr, rr = gatetype*2 + dlocal. Weights staged in LDS (padded).
#define WPAD 520
__global__ void __launch_bounds__(256) gates_k(const _Float16* __restrict__ Wih_h,
    const _Float16* __restrict__ Whh_h, const float* __restrict__ Xg,
    const _Float16* __restrict__ ctx_h, const _Float16* __restrict__ h_in,
    _Float16* __restrict__ h_out, float* __restrict__ c_state,
    _Float16* __restrict__ H_h, int t) {
  __shared__ _Float16 wc[8*WPAD];
  __shared__ _Float16 wh[8*WPAD];
  __shared__ float gl[256];
  int g = blockIdx.x, tid = threadIdx.x;
  int d0 = g*2;
  for (int idx = tid; idx < 8*64; idx += 256) {
    int r = idx >> 6, c8 = (idx & 63)*8;
    int typ = r >> 1, dl = r & 1;
    size_t i_row = (size_t)(typ*DD + d0 + dl);
    *(half8_t*)(wc + r*WPAD + c8) = *(const half8_t*)(Wih_h + i_row*1024 + 512 + c8);
    *(half8_t*)(wh + r*WPAD + c8) = *(const half8_t*)(Whh_h + i_row*DD + c8);
  }
  __syncthreads();
  int b = tid >> 3, rr = tid & 7;
  int typ = rr >> 1, dl = rr & 1;
  int i_row = typ*DD + d0 + dl;
  float acc = Xg[((size_t)t*NB + b)*NG + i_row];
  {
    const half2_t* wcp = (const half2_t*)(wc + rr*WPAD);
    const half2_t* whp = (const half2_t*)(wh + rr*WPAD);
    const half8_t* cg = (const half8_t*)(ctx_h + b*DE);
    const half8_t* hg = (const half8_t*)(h_in + b*DD);
    for (int k8 = 0; k8 < 64; k8++) {
      half8_t c8v = cg[k8];
      half8_t h8v = hg[k8];
      const half2_t* cp = (const half2_t*)&c8v;
      const half2_t* hp = (const half2_t*)&h8v;
      int kb = k8*4;
      acc = fdot2f(wcp[kb+0], cp[0], acc);
      acc = fdot2f(wcp[kb+1], cp[1], acc);
      acc = fdot2f(wcp[kb+2], cp[2], acc);
      acc = fdot2f(wcp[kb+3], cp[3], acc);
      acc = fdot2f(whp[kb+0], hp[0], acc);
      acc = fdot2f(whp[kb+1], hp[1], acc);
      acc = fdot2f(whp[kb+2], hp[2], acc);
      acc = fdot2f(whp[kb+3], hp[3], acc);
    }
  }
  gl[tid] = acc;
  __syncthreads();
  if (tid < 64) {
    int bb = tid >> 1, d2 = tid & 1;
    int dI = d0 + d2;
    float ig = gl[bb*8 + 0 + d2];
    float fg = gl[bb*8 + 2 + d2];
    float gg = gl[bb*8 + 4 + d2];
    float og = gl[bb*8 + 6 + d2];
    float co = c_state[bb*DD + dI];
    float cn = fast_sig(fg)*co + fast_sig(ig)*fast_tanh(gg);
    float hn = fast_sig(og)*fast_tanh(cn);
    c_state[bb*DD + dI] = cn;
    _Float16 hh = (_Float16)hn;
    h_out[bb*DD + dI] = hh;
    H_h[((size_t)t*NB + bb)*DD + dI] = hh;
  }
}

// Generic C = A * B^T (+bias), fp16 inputs, fp32 accumulate via MFMA 16x16x32.
// A: [M, lda] fp16 row-major; B: [N, ldb] fp16 row-major; grid (N/128, M/128), 4 waves,
// each wave an independent 64x64 tile. MODE 0: fp32 C (+bias). MODE 1: fp16 C.
// MODE 2: fp32 C (+bias) with row remap r=t*32+b -> out row b*64+t (logits layout).
template<int MODE>
__global__ void __launch_bounds__(256) gemm_abt_k(const _Float16* __restrict__ A, int lda,
    const _Float16* __restrict__ B, int ldb, void* __restrict__ Cp, int ldc,
    const float* __restrict__ bias, int K) {
  int wave = threadIdx.x >> 6, lane = threadIdx.x & 63;
  int m0 = blockIdx.y*128 + (wave >> 1)*64;
  int n0 = blockIdx.x*128 + (wave & 1)*64;
  int lr = lane & 15, quad = lane >> 4;
  float4_t acc[4][4];
  #pragma unroll
  for (int i = 0; i < 4; i++)
    #pragma unroll
    for (int j = 0; j < 4; j++)
      acc[i][j] = (float4_t){0.f, 0.f, 0.f, 0.f};
  const _Float16* Ap = A + (size_t)(m0 + lr)*lda + quad*8;
  const _Float16* Bp = B + (size_t)(n0 + lr)*ldb + quad*8;
  for (int k0 = 0; k0 < K; k0 += 32) {
    half8_t af[4], bf[4];
    #pragma unroll
    for (int i = 0; i < 4; i++) af[i] = *(const half8_t*)(Ap + (size_t)i*16*lda + k0);
    #pragma unroll
    for (int i = 0; i < 4; i++) bf[i] = *(const half8_t*)(Bp + (size_t)i*16*ldb + k0);
    #pragma unroll
    for (int mi = 0; mi < 4; mi++)
      #pragma unroll
      for (int ni = 0; ni < 4; ni++)
        acc[mi][ni] = __builtin_amdgcn_mfma_f32_16x16x32_f16(af[mi], bf[ni], acc[mi][ni], 0, 0, 0);
  }
  #pragma unroll
  for (int mi = 0; mi < 4; mi++) {
    #pragma unroll
    for (int ni = 0; ni < 4; ni++) {
      int col = n0 + ni*16 + lr;
      float bv = (MODE == 1) ? 0.f : bias[col];
      #pragma unroll
      for (int r = 0; r < 4; r++) {
        int row = m0 + mi*16 + quad*4 + r;
        if (MODE == 1) {
          ((_Float16*)Cp)[(size_t)row*ldc + col] = (_Float16)acc[mi][ni][r];
        } else if (MODE == 0) {
          ((float*)Cp)[(size_t)row*ldc + col] = acc[mi][ni][r] + bv;
        } else {
          size_t orow = (size_t)((row & 31)*NT + (row >> 5));
          ((float*)Cp)[orow*ldc + col] = acc[mi][ni][r] + bv;
        }
      }
    }
  }
}

extern "C" void kernel_launch(void* const* d_in, const int* in_sizes, int n_in,
                              void* d_out, int out_size, void* d_ws, size_t ws_size,
                              hipStream_t stream) {
  const float* imgf  = (const float*)d_in[0];
  const int*   cap   = (const int*)d_in[1];
  const float* emb   = (const float*)d_in[2];
  const float* Wh0   = (const float*)d_in[3];
  const float* bh0   = (const float*)d_in[4];
  const float* Wc0   = (const float*)d_in[5];
  const float* bc0   = (const float*)d_in[6];
  const float* Wenc  = (const float*)d_in[7];
  const float* Wdec  = (const float*)d_in[8];
  const float* v_att = (const float*)d_in[9];
  const float* W_ih  = (const float*)d_in[10];
  const float* b_ih  = (const float*)d_in[11];
  const float* W_hh  = (const float*)d_in[12];
  const float* b_hh  = (const float*)d_in[13];
  const float* Wfc   = (const float*)d_in[14];
  const float* bfc   = (const float*)d_in[15];
  float* out = (float*)d_out;
  (void)in_sizes; (void)n_in; (void)out_size; (void)ws_size;

  char* ws = (char*)d_ws;
  size_t off = 0;
  auto alloc = [&](size_t bytes) -> void* {
    void* p = ws + off;
    off += (bytes + 255) & ~(size_t)255;
    return p;
  };
  _Float16* Wenc_h  = (_Float16*)alloc((size_t)512*512*2);
  _Float16* Wdec_h  = (_Float16*)alloc((size_t)512*512*2);
  _Float16* Wih_h   = (_Float16*)alloc((size_t)2048*1024*2);
  _Float16* Whh_h   = (_Float16*)alloc((size_t)2048*512*2);
  _Float16* Wfc_h   = (_Float16*)alloc((size_t)32000*512*2);
  _Float16* imgf_h  = (_Float16*)alloc((size_t)32*196*512*2);
  _Float16* fproj_h = (_Float16*)alloc((size_t)32*196*512*2);
  _Float16* X_h     = (_Float16*)alloc((size_t)64*32*512*2);
  float*    Xg      = (float*)alloc((size_t)64*32*2048*4);
  float*    bsum    = (float*)alloc((size_t)2048*4);
  float*    c_state = (float*)alloc((size_t)32*512*4);
  _Float16* hbuf0   = (_Float16*)alloc((size_t)32*512*2);
  _Float16* hbuf1   = (_Float16*)alloc((size_t)32*512*2);
  _Float16* ctx_h   = (_Float16*)alloc((size_t)32*512*2);
  _Float16* H_h     = (_Float16*)alloc((size_t)2048*512*2);

  auto cvt = [&](const float* s, _Float16* d, int n) {
    cvt_k<<<dim3((n/4 + 255)/256), dim3(256), 0, stream>>>(s, d, n);
  };
  cvt(Wenc, Wenc_h, 512*512);
  cvt(Wdec, Wdec_h, 512*512);
  cvt(W_ih, Wih_h, 2048*1024);
  cvt(W_hh, Whh_h, 2048*512);
  cvt(Wfc,  Wfc_h, 32000*512);
  cvt(imgf, imgf_h, 32*196*512);
  bias_sum_k<<<dim3(8), dim3(256), 0, stream>>>(b_ih, b_hh, bsum);
  gather_emb_k<<<dim3(2048), dim3(256), 0, stream>>>(emb, cap, X_h);
  init_state_k<<<dim3(32), dim3(256), 0, stream>>>(imgf, Wh0, bh0, Wc0, bc0, c_state, hbuf0);
  // feat_proj = image_features @ Wenc^T  -> fp16 [32*196, 512]
  gemm_abt_k<1><<<dim3(4, 49), dim3(256), 0, stream>>>(imgf_h, 512, Wenc_h, 512, fproj_h, 512, nullptr, 512);
  // Xg = emb_x @ W_ih[:, :512]^T + (b_ih + b_hh)  -> fp32 [2048, 2048]
  gemm_abt_k<0><<<dim3(16, 16), dim3(256), 0, stream>>>(X_h, 512, Wih_h, 1024, Xg, 2048, bsum, 512);

  float* out_alpha = out + (size_t)32*64*32000;
  for (int t = 0; t < 64; t++) {
    _Float16* hin  = (t & 1) ? hbuf1 : hbuf0;
    _Float16* hout = (t & 1) ? hbuf0 : hbuf1;
    att_k<<<dim3(32), dim3(512), 0, stream>>>(hin, Wdec_h, fproj_h, imgf_h, v_att, ctx_h, out_alpha, t);
    gates_k<<<dim3(256), dim3(256), 0, stream>>>(Wih_h, Whh_h, Xg, ctx_h, hin, hout, c_state, H_h, t);
  }
  // outputs = H @ Wfc^T + bfc, rows r=t*32+b remapped to out[b,t,:]
  gemm_abt_k<2><<<dim3(250, 16), dim3(256), 0, stream>>>(H_h, 512, Wfc_h, 512, out, 32000, bfc, 512);
}